// Round 3
// baseline (40073.972 us; speedup 1.0000x reference)
//
#include <hip/hip_runtime.h>
#include <hip/hip_cooperative_groups.h>
#include <cmath>

namespace cg = cooperative_groups;

constexpr int B = 256, T = 1024, D = 128, H = 256, NC = 10;
constexpr int K = D + H;                          // 384

// ws layout (floats): hbuf[2][H][B] @ 0 (h ping-pong, transposed), wrep @ WREP_OFF
constexpr size_t HBUF_OFF = 0;
constexpr size_t WREP_OFF = 2ull * H * B;               // 131072
constexpr size_t WREP_ELEMS = 64ull * K * 16;           // 393216

__device__ __forceinline__ float fast_sig(float x) { return 1.f / (1.f + __expf(-x)); }
__device__ __forceinline__ float fast_tanh(float x) {
  float ax = fabsf(x);
  float e = __expf(2.f * ax);            // overflow -> inf -> r -> 1, safe
  float r = 1.f - 2.f / (e + 1.f);
  return copysignf(r, x);
}

// One-time: zero h0; repack weights into wrep[cb][k][g*4+jj].
__global__ void setup_kernel(const float* __restrict__ wgx, const float* __restrict__ wgh,
                             const float* __restrict__ wix, const float* __restrict__ wih,
                             const float* __restrict__ wfx, const float* __restrict__ wfh,
                             const float* __restrict__ wox, const float* __restrict__ woh,
                             float* __restrict__ ws) {
  int idx = blockIdx.x * blockDim.x + threadIdx.x;       // 0 .. 393215
  if (idx < (int)(2 * H * B)) ws[HBUF_OFF + idx] = 0.f;  // h_0 = 0 (both buffers, why not)
  const float* wxs[4] = {wgx, wix, wfx, wox};
  const float* whs[4] = {wgh, wih, wfh, woh};
  int c  = idx & 15;
  int r  = (idx >> 4) % K;
  int cb = idx / (K * 16);
  int g  = c >> 2, jj = c & 3;
  int j  = cb * 4 + jj;
  float v = (r < D) ? wxs[g][r * H + j] : whs[g][(r - D) * H + j];
  ws[WREP_OFF + idx] = v;
}

#define FMA16(a, wptr) { \
  const float4* _wv = (const float4*)(wptr); \
  float4 w0 = _wv[0], w1 = _wv[1], w2 = _wv[2], w3 = _wv[3]; \
  acc[0]  += (a) * w0.x; acc[1]  += (a) * w0.y; acc[2]  += (a) * w0.z; acc[3]  += (a) * w0.w; \
  acc[4]  += (a) * w1.x; acc[5]  += (a) * w1.y; acc[6]  += (a) * w1.z; acc[7]  += (a) * w1.w; \
  acc[8]  += (a) * w2.x; acc[9]  += (a) * w2.y; acc[10] += (a) * w2.z; acc[11] += (a) * w2.w; \
  acc[12] += (a) * w3.x; acc[13] += (a) * w3.y; acc[14] += (a) * w3.z; acc[15] += (a) * w3.w; }

// Persistent: all T steps in one cooperative launch. Grid 256 = 4 bq x 64 cb.
// 256 threads = 4 waves (K-split); lane = local batch. Weights LDS-resident.
__launch_bounds__(256, 1)
__global__ void lstm_persistent(const float* __restrict__ x,
                                const float* __restrict__ bg, const float* __restrict__ bi,
                                const float* __restrict__ bf, const float* __restrict__ bo,
                                float* __restrict__ ws) {
  __shared__ float A[128][64];                 // 32 KB h-stage; epilogue aliases as Zp
  __shared__ float Wl[K][16];                  // 24 KB weight slice, loaded once
  float* Zp = &A[0][0];                        // Zp[w][c][64]: 4096 floats <= 8192

  cg::grid_group grid = cg::this_grid();

  const int bq = blockIdx.x >> 6;
  const int cb = blockIdx.x & 63;
  const int b0 = bq * 64;
  const int t_ = threadIdx.x;
  const int w = t_ >> 6, lane = t_ & 63;

  // ---- weights -> LDS, once ----
  const float* wslice = ws + WREP_OFF + (size_t)cb * (K * 16);
  #pragma unroll
  for (int i = 0; i < 6; ++i) {
    int i4 = t_ + i * 256;                     // 0 .. 1535 float4s
    ((float4*)&Wl[0][0])[i4] = ((const float4*)wslice)[i4];
  }

  // epilogue identity: thread owns (h-col jglob, batch b0+lane) for the whole run
  const int jglob = cb * 4 + w;
  const float bias_g = bg[jglob], bias_i = bi[jglob];
  const float bias_f = bf[jglob], bias_o = bo[jglob];
  float c_state = 0.f;
  __syncthreads();

  for (int t = 0; t < T; ++t) {
    const float* hread  = ws + HBUF_OFF + (size_t)(t & 1) * (H * B);
    float*       hwrite = ws + HBUF_OFF + (size_t)((t + 1) & 1) * (H * B);

    // ---- issue all global loads up front (x rows, h-lo, h-hi) ----
    const float* xb = x + ((size_t)(b0 + lane) * T + t) * D + w * 32;
    float4 xr[8];
    #pragma unroll
    for (int i = 0; i < 8; ++i) xr[i] = ((const float4*)xb)[i];

    float4 hlo[8], hhi[8];
    #pragma unroll
    for (int i = 0; i < 8; ++i) {
      int fid = t_ + i * 256;                  // 0..2047
      int r = fid >> 4, b4 = (fid & 15) << 2;
      hlo[i] = *(const float4*)(hread + (size_t)r * B + b0 + b4);
      hhi[i] = *(const float4*)(hread + (size_t)(128 + r) * B + b0 + b4);
    }

    float acc[16];
    #pragma unroll
    for (int c = 0; c < 16; ++c) acc[c] = 0.f;

    // ---- phase 0: h rows 0..127 ----
    #pragma unroll
    for (int i = 0; i < 8; ++i) {
      int fid = t_ + i * 256;
      int r = fid >> 4, b4 = (fid & 15) << 2;
      *(float4*)&A[r][b4] = hlo[i];
    }
    __syncthreads();
    #pragma unroll 8
    for (int kk = 0; kk < 32; ++kk) {
      float a = A[w * 32 + kk][lane];
      FMA16(a, &Wl[D + w * 32 + kk][0]);
    }
    // ---- x contribution from registers (k rows w*32 .. w*32+31) ----
    #pragma unroll
    for (int i = 0; i < 8; ++i) {
      FMA16(xr[i].x, &Wl[w * 32 + i * 4 + 0][0]);
      FMA16(xr[i].y, &Wl[w * 32 + i * 4 + 1][0]);
      FMA16(xr[i].z, &Wl[w * 32 + i * 4 + 2][0]);
      FMA16(xr[i].w, &Wl[w * 32 + i * 4 + 3][0]);
    }
    __syncthreads();

    // ---- phase 1: h rows 128..255 (data already in registers) ----
    #pragma unroll
    for (int i = 0; i < 8; ++i) {
      int fid = t_ + i * 256;
      int r = fid >> 4, b4 = (fid & 15) << 2;
      *(float4*)&A[r][b4] = hhi[i];
    }
    __syncthreads();
    #pragma unroll 8
    for (int kk = 0; kk < 32; ++kk) {
      float a = A[w * 32 + kk][lane];
      FMA16(a, &Wl[D + 128 + w * 32 + kk][0]);
    }
    __syncthreads();

    // ---- K-split partial exchange via LDS (aliases A) ----
    #pragma unroll
    for (int c = 0; c < 16; ++c) Zp[(w * 16 + c) * 64 + lane] = acc[c];
    __syncthreads();

    // ---- epilogue ----
    float z0 = 0.f, z1 = 0.f, z2 = 0.f, z3 = 0.f;
    #pragma unroll
    for (int ww = 0; ww < 4; ++ww) {
      z0 += Zp[(ww * 16 + 0 * 4 + w) * 64 + lane];
      z1 += Zp[(ww * 16 + 1 * 4 + w) * 64 + lane];
      z2 += Zp[(ww * 16 + 2 * 4 + w) * 64 + lane];
      z3 += Zp[(ww * 16 + 3 * 4 + w) * 64 + lane];
    }
    float gg = fast_tanh(z0 + bias_g);
    float ii = fast_sig (z1 + bias_i);
    float ff = fast_sig (z2 + bias_f);
    float oo = fast_sig (z3 + bias_o);
    c_state = gg * ii + c_state * ff;
    hwrite[(size_t)jglob * B + b0 + lane] = fast_tanh(c_state) * oo;

    grid.sync();
  }
}

// out[b][c] = sum_j h[j][b] * wph[j][c] + bp[c]
__global__ void proj_kernel(const float* __restrict__ hT, const float* __restrict__ wph,
                            const float* __restrict__ bp, float* __restrict__ out) {
  int b = blockIdx.x;
  int j = threadIdx.x;
  float hv = hT[(size_t)j * B + b];
  float p[NC];
  #pragma unroll
  for (int c = 0; c < NC; ++c) p[c] = hv * wph[j * NC + c];
  #pragma unroll
  for (int off = 32; off >= 1; off >>= 1)
    #pragma unroll
    for (int c = 0; c < NC; ++c) p[c] += __shfl_xor(p[c], off, 64);
  __shared__ float s[NC];
  if (threadIdx.x < NC) s[threadIdx.x] = 0.f;
  __syncthreads();
  if ((threadIdx.x & 63) == 0)
    for (int c = 0; c < NC; ++c) atomicAdd(&s[c], p[c]);
  __syncthreads();
  if (j < NC) out[b * NC + j] = s[j] + bp[j];
}

extern "C" void kernel_launch(void* const* d_in, const int* in_sizes, int n_in,
                              void* d_out, int out_size, void* d_ws, size_t ws_size,
                              hipStream_t stream) {
  const float* x   = (const float*)d_in[0];
  const float* wgx = (const float*)d_in[1];
  const float* wgh = (const float*)d_in[2];
  const float* bg  = (const float*)d_in[3];
  const float* wix = (const float*)d_in[4];
  const float* wih = (const float*)d_in[5];
  const float* bi  = (const float*)d_in[6];
  const float* wfx = (const float*)d_in[7];
  const float* wfh = (const float*)d_in[8];
  const float* bf  = (const float*)d_in[9];
  const float* wox = (const float*)d_in[10];
  const float* woh = (const float*)d_in[11];
  const float* bo  = (const float*)d_in[12];
  const float* wph = (const float*)d_in[13];
  const float* bp  = (const float*)d_in[14];
  float* out = (float*)d_out;
  float* ws  = (float*)d_ws;

  setup_kernel<<<(int)(WREP_ELEMS / 256), 256, 0, stream>>>(wgx, wgh, wix, wih,
                                                            wfx, wfh, wox, woh, ws);

  void* args[] = {(void*)&x, (void*)&bg, (void*)&bi, (void*)&bf, (void*)&bo, (void*)&ws};
  hipLaunchCooperativeKernel(reinterpret_cast<void*>(lstm_persistent),
                             dim3(256), dim3(256), args, 0, stream);

  // final h is in buffer (T & 1) = 0
  proj_kernel<<<B, H, 0, stream>>>(ws + HBUF_OFF, wph, bp, out);
}

// Round 5
// 21385.684 us; speedup vs baseline: 1.8739x; 1.8739x over previous
//
#include <hip/hip_runtime.h>
#include <cmath>

constexpr int B = 256, T = 1024, D = 128, H = 256, NC = 10;
constexpr int K = D + H;                          // 384

// ws layout (floats): hbuf[2][H][B] @ 0 (transposed h ping-pong), wrep, barrier counters
constexpr size_t HBUF_OFF = 0;
constexpr size_t WREP_OFF = 2ull * H * B;               // 131072
constexpr size_t WREP_ELEMS = 64ull * K * 16;           // 393216
constexpr size_t BAR_OFF  = WREP_OFF + WREP_ELEMS;      // 4 counters, 64 words apart

__device__ __forceinline__ float fast_sig(float x) { return 1.f / (1.f + __expf(-x)); }
__device__ __forceinline__ float fast_tanh(float x) {
  float ax = fabsf(x);
  float e = __expf(2.f * ax);            // overflow -> inf -> r -> 1, safe
  float r = 1.f - 2.f / (e + 1.f);
  return copysignf(r, x);
}

// One-time per launch: zero h0 + barrier counters; repack weights wrep[cb][k][g*4+jj].
__global__ void setup_kernel(const float* __restrict__ wgx, const float* __restrict__ wgh,
                             const float* __restrict__ wix, const float* __restrict__ wih,
                             const float* __restrict__ wfx, const float* __restrict__ wfh,
                             const float* __restrict__ wox, const float* __restrict__ woh,
                             float* __restrict__ ws) {
  int idx = blockIdx.x * blockDim.x + threadIdx.x;       // 0 .. 393215
  if (idx < (int)(H * B)) ws[HBUF_OFF + idx] = 0.f;      // h_0 = 0 (buffer 0)
  if (idx < 256) ((unsigned*)(ws + BAR_OFF))[idx] = 0u;  // barrier counters
  const float* wxs[4] = {wgx, wix, wfx, wox};
  const float* whs[4] = {wgh, wih, wfh, woh};
  int c  = idx & 15;
  int r  = (idx >> 4) % K;
  int cb = idx / (K * 16);
  int g  = c >> 2, jj = c & 3;
  int j  = cb * 4 + jj;
  float v = (r < D) ? wxs[g][r * H + j] : whs[g][(r - D) * H + j];
  ws[WREP_OFF + idx] = v;
}

#define FMA16(a, wptr) { \
  const float4* _wv = (const float4*)(wptr); \
  float4 w0 = _wv[0], w1 = _wv[1], w2 = _wv[2], w3 = _wv[3]; \
  acc[0]  += (a) * w0.x; acc[1]  += (a) * w0.y; acc[2]  += (a) * w0.z; acc[3]  += (a) * w0.w; \
  acc[4]  += (a) * w1.x; acc[5]  += (a) * w1.y; acc[6]  += (a) * w1.z; acc[7]  += (a) * w1.w; \
  acc[8]  += (a) * w2.x; acc[9]  += (a) * w2.y; acc[10] += (a) * w2.z; acc[11] += (a) * w2.w; \
  acc[12] += (a) * w3.x; acc[13] += (a) * w3.y; acc[14] += (a) * w3.z; acc[15] += (a) * w3.w; }

// 64-WG group barrier from HW-verified primitives only:
//   arrival: device-scope atomicAdd (G12/m20); spin: atomicAdd(cnt,0) RMW --
//   always serviced at the coherence point, cannot read a stale cached value;
//   release/acquire: __threadfence (agent-scope wb + inv).
__device__ __forceinline__ void group_barrier(unsigned* cnt, unsigned target) {
  __syncthreads();                     // all WG stores issued & drained (vmcnt) per wave
  if (threadIdx.x == 0) {
    __threadfence();                   // release: WG's h slice -> coherence point
    atomicAdd(cnt, 1u);
    while (atomicAdd(cnt, 0u) < target)
      __builtin_amdgcn_s_sleep(8);     // ~0.2 us poll spacing
    __threadfence();                   // acquire: invalidate stale L1/L2 lines
  }
  __syncthreads();
}

// Persistent: all T steps. Grid 256 = 4 bq-groups x 64 cb. 256 thr = 4 waves (K-split).
// lane = local batch. Weights LDS-resident; h exchanged through ws, per-group barrier.
// Residency: 56 KB LDS -> <=2 WG/CU -> capacity 512 >= 256 WGs -> all resident, no deadlock.
__launch_bounds__(256, 1)
__global__ void lstm_persistent(const float* __restrict__ x,
                                const float* __restrict__ bg, const float* __restrict__ bi,
                                const float* __restrict__ bf, const float* __restrict__ bo,
                                float* __restrict__ ws) {
  __shared__ float A[128][64];                 // 32 KB h-stage; epilogue aliases as Zp
  __shared__ float Wl[K][16];                  // 24 KB weight slice, loaded once
  float* Zp = &A[0][0];                        // Zp needs 4096 floats <= 8192

  const int bq = blockIdx.x >> 6;
  const int cb = blockIdx.x & 63;
  const int b0 = bq * 64;
  const int t_ = threadIdx.x;
  const int w = t_ >> 6, lane = t_ & 63;
  unsigned* cnt = (unsigned*)(ws + BAR_OFF) + bq * 64;   // per-group counter, 256B apart

  // ---- weights -> LDS, once ----
  const float* wslice = ws + WREP_OFF + (size_t)cb * (K * 16);
  #pragma unroll
  for (int i = 0; i < 6; ++i) {
    int i4 = t_ + i * 256;                     // 0 .. 1535 float4s
    ((float4*)&Wl[0][0])[i4] = ((const float4*)wslice)[i4];
  }

  const int jglob = cb * 4 + w;                // epilogue identity: (col jglob, batch b0+lane)
  const float bias_g = bg[jglob], bias_i = bi[jglob];
  const float bias_f = bf[jglob], bias_o = bo[jglob];
  float c_state = 0.f;
  __syncthreads();

  for (int t = 0; t < T; ++t) {
    const float* hread  = ws + HBUF_OFF + (size_t)(t & 1) * (H * B);
    float*       hwrite = ws + HBUF_OFF + (size_t)((t + 1) & 1) * (H * B);

    // ---- issue all global loads up front (x rows, h-lo, h-hi) ----
    const float* xb = x + ((size_t)(b0 + lane) * T + t) * D + w * 32;
    float4 xr[8];
    #pragma unroll
    for (int i = 0; i < 8; ++i) xr[i] = ((const float4*)xb)[i];

    float4 hlo[8], hhi[8];
    #pragma unroll
    for (int i = 0; i < 8; ++i) {
      int fid = t_ + i * 256;                  // 0..2047
      int r = fid >> 4, b4 = (fid & 15) << 2;
      hlo[i] = *(const float4*)(hread + (size_t)r * B + b0 + b4);
      hhi[i] = *(const float4*)(hread + (size_t)(128 + r) * B + b0 + b4);
    }

    float acc[16];
    #pragma unroll
    for (int c = 0; c < 16; ++c) acc[c] = 0.f;

    // ---- phase 0: h rows 0..127 ----
    #pragma unroll
    for (int i = 0; i < 8; ++i) {
      int fid = t_ + i * 256;
      int r = fid >> 4, b4 = (fid & 15) << 2;
      *(float4*)&A[r][b4] = hlo[i];
    }
    __syncthreads();
    #pragma unroll 8
    for (int kk = 0; kk < 32; ++kk) {
      float a = A[w * 32 + kk][lane];
      FMA16(a, &Wl[D + w * 32 + kk][0]);
    }
    // ---- x contribution from registers (k rows w*32 .. w*32+31) ----
    #pragma unroll
    for (int i = 0; i < 8; ++i) {
      FMA16(xr[i].x, &Wl[w * 32 + i * 4 + 0][0]);
      FMA16(xr[i].y, &Wl[w * 32 + i * 4 + 1][0]);
      FMA16(xr[i].z, &Wl[w * 32 + i * 4 + 2][0]);
      FMA16(xr[i].w, &Wl[w * 32 + i * 4 + 3][0]);
    }
    __syncthreads();

    // ---- phase 1: h rows 128..255 (data already in registers) ----
    #pragma unroll
    for (int i = 0; i < 8; ++i) {
      int fid = t_ + i * 256;
      int r = fid >> 4, b4 = (fid & 15) << 2;
      *(float4*)&A[r][b4] = hhi[i];
    }
    __syncthreads();
    #pragma unroll 8
    for (int kk = 0; kk < 32; ++kk) {
      float a = A[w * 32 + kk][lane];
      FMA16(a, &Wl[D + 128 + w * 32 + kk][0]);
    }
    __syncthreads();

    // ---- K-split partial exchange via LDS (aliases A) ----
    #pragma unroll
    for (int c = 0; c < 16; ++c) Zp[(w * 16 + c) * 64 + lane] = acc[c];
    __syncthreads();

    // ---- epilogue ----
    float z0 = 0.f, z1 = 0.f, z2 = 0.f, z3 = 0.f;
    #pragma unroll
    for (int ww = 0; ww < 4; ++ww) {
      z0 += Zp[(ww * 16 + 0 * 4 + w) * 64 + lane];
      z1 += Zp[(ww * 16 + 1 * 4 + w) * 64 + lane];
      z2 += Zp[(ww * 16 + 2 * 4 + w) * 64 + lane];
      z3 += Zp[(ww * 16 + 3 * 4 + w) * 64 + lane];
    }
    float gg = fast_tanh(z0 + bias_g);
    float ii = fast_sig (z1 + bias_i);
    float ff = fast_sig (z2 + bias_f);
    float oo = fast_sig (z3 + bias_o);
    c_state = gg * ii + c_state * ff;
    hwrite[(size_t)jglob * B + b0 + lane] = fast_tanh(c_state) * oo;

    group_barrier(cnt, 64u * (unsigned)(t + 1));
  }
}

// out[b][c] = sum_j h[j][b] * wph[j][c] + bp[c]
__global__ void proj_kernel(const float* __restrict__ hT, const float* __restrict__ wph,
                            const float* __restrict__ bp, float* __restrict__ out) {
  int b = blockIdx.x;
  int j = threadIdx.x;
  float hv = hT[(size_t)j * B + b];
  float p[NC];
  #pragma unroll
  for (int c = 0; c < NC; ++c) p[c] = hv * wph[j * NC + c];
  #pragma unroll
  for (int off = 32; off >= 1; off >>= 1)
    #pragma unroll
    for (int c = 0; c < NC; ++c) p[c] += __shfl_xor(p[c], off, 64);
  __shared__ float s[NC];
  if (threadIdx.x < NC) s[threadIdx.x] = 0.f;
  __syncthreads();
  if ((threadIdx.x & 63) == 0)
    for (int c = 0; c < NC; ++c) atomicAdd(&s[c], p[c]);
  __syncthreads();
  if (j < NC) out[b * NC + j] = s[j] + bp[j];
}

extern "C" void kernel_launch(void* const* d_in, const int* in_sizes, int n_in,
                              void* d_out, int out_size, void* d_ws, size_t ws_size,
                              hipStream_t stream) {
  const float* x   = (const float*)d_in[0];
  const float* wgx = (const float*)d_in[1];
  const float* wgh = (const float*)d_in[2];
  const float* bg  = (const float*)d_in[3];
  const float* wix = (const float*)d_in[4];
  const float* wih = (const float*)d_in[5];
  const float* bi  = (const float*)d_in[6];
  const float* wfx = (const float*)d_in[7];
  const float* wfh = (const float*)d_in[8];
  const float* bf  = (const float*)d_in[9];
  const float* wox = (const float*)d_in[10];
  const float* woh = (const float*)d_in[11];
  const float* bo  = (const float*)d_in[12];
  const float* wph = (const float*)d_in[13];
  const float* bp  = (const float*)d_in[14];
  float* out = (float*)d_out;
  float* ws  = (float*)d_ws;

  setup_kernel<<<(int)(WREP_ELEMS / 256), 256, 0, stream>>>(wgx, wgh, wix, wih,
                                                            wfx, wfh, wox, woh, ws);

  lstm_persistent<<<256, 256, 0, stream>>>(x, bg, bi, bf, bo, ws);

  // final h is in buffer ((T-1)+1)&1 = 0
  proj_kernel<<<B, H, 0, stream>>>(ws + HBUF_OFF, wph, bp, out);
}